// Round 1
// baseline (674.453 us; speedup 1.0000x reference)
//
#include <hip/hip_runtime.h>

#define NNODES 307
#define HEADS 8
#define HDV 64
#define DM 512
#define BATCH 8
#define TSTEPS 12
#define MROWS (BATCH*TSTEPS*NNODES)   // 29472

typedef unsigned short u16;
typedef __attribute__((ext_vector_type(8))) short s16x8;
typedef __attribute__((ext_vector_type(8))) unsigned short u16x8;
typedef __attribute__((ext_vector_type(4))) float f32x4;

__device__ __forceinline__ u16 f2bf(float f){
  unsigned int u = __builtin_bit_cast(unsigned int, f);
  u += 0x7fffu + ((u >> 16) & 1u);   // RNE; inputs finite
  return (u16)(u >> 16);
}

// ---------------- weight transpose + bf16 convert: Wt[n][k] = W[k][n] ----------------
struct PrepArgs { const float* w[4]; u16* o[4]; };

__global__ __launch_bounds__(256)
void prep_w(PrepArgs a){
  const float* w = a.w[blockIdx.z];
  u16* o = a.o[blockIdx.z];
  __shared__ float tile[32][33];
  int bx = blockIdx.x*32, by = blockIdx.y*32;
  int tx = threadIdx.x, ty = threadIdx.y;
  for (int i = ty; i < 32; i += 8)
    tile[i][tx] = w[(size_t)(by+i)*DM + bx + tx];
  __syncthreads();
  for (int i = ty; i < 32; i += 8)
    o[(size_t)(bx+i)*DM + by + tx] = f2bf(tile[tx][i]);
}

// ---------------- row softmax of semantic matrix (fp32) ----------------
__global__ __launch_bounds__(256)
void mask_softmax(const float* __restrict__ sem, float* __restrict__ mask){
  int n = blockIdx.x;
  int tid = threadIdx.x, lane = tid & 63, wid = tid >> 6;
  __shared__ float red[4];
  float v0 = (tid < NNODES) ? sem[(size_t)n*NNODES + tid] : -INFINITY;
  float v1 = (tid + 256 < NNODES) ? sem[(size_t)n*NNODES + tid + 256] : -INFINITY;
  float mx = fmaxf(v0, v1);
  for (int d = 1; d < 64; d <<= 1) mx = fmaxf(mx, __shfl_xor(mx, d));
  if (lane == 0) red[wid] = mx;
  __syncthreads();
  mx = fmaxf(fmaxf(red[0], red[1]), fmaxf(red[2], red[3]));
  __syncthreads();
  float e0 = (tid < NNODES) ? __expf(v0 - mx) : 0.f;
  float e1 = (tid + 256 < NNODES) ? __expf(v1 - mx) : 0.f;
  float s = e0 + e1;
  for (int d = 1; d < 64; d <<= 1) s += __shfl_xor(s, d);
  if (lane == 0) red[wid] = s;
  __syncthreads();
  s = red[0] + red[1] + red[2] + red[3];
  float rinv = 1.f / s;
  if (tid < NNODES) mask[(size_t)n*NNODES + tid] = e0 * rinv;
  if (tid + 256 < NNODES) mask[(size_t)n*NNODES + tid + 256] = e1 * rinv;
}

// ---------------- generic 512-K GEMM: C[M,512] = A[M,512] @ W + bias ----------------
// Wt is pre-transposed bf16 [512][512] (Wt[n][k] = W[k][n]).
// LDS tiles XOR-swizzled: byte = row*128 + (kbyte ^ ((row&7)<<4)), kbyte in 16B slots.
struct GemmSet { const void* A; const u16* W; const float* bias; void* C; };
struct GemmArgs { GemmSet s[3]; };

template<int AF32, int CBF16>
__global__ __launch_bounds__(256)
void gemm512(GemmArgs ga, int M){
  GemmSet g = ga.s[blockIdx.z];
  __shared__ u16 As[128*64];
  __shared__ u16 Bs[128*64];
  const int tid = threadIdx.x;
  const int lane = tid & 63;
  const int wid = tid >> 6;
  const int m0 = blockIdx.x * 128;
  const int n0 = blockIdx.y * 128;
  const int wr = (wid >> 1) * 64;
  const int wc = (wid & 1) * 64;

  const f32x4 fz = {0.f, 0.f, 0.f, 0.f};
  f32x4 acc[4][4];
#pragma unroll
  for (int i = 0; i < 4; i++)
#pragma unroll
    for (int j = 0; j < 4; j++) acc[i][j] = fz;

  const int sr = tid >> 1;      // stage row 0..127
  const int shf = tid & 1;      // which 32-element half
  const int grA = m0 + sr;
  const bool okA = grA < M;
  const u16x8 zu = {0,0,0,0,0,0,0,0};

  for (int k0 = 0; k0 < 512; k0 += 64) {
    // ---- stage A tile (fp32->bf16 or bf16 passthrough) ----
    {
      u16x8 ch[4];
      if constexpr (AF32) {
        const float* src = (const float*)g.A + (size_t)grA*DM + k0 + shf*32;
#pragma unroll
        for (int i = 0; i < 4; i++) {
          float4 f0 = okA ? ((const float4*)src)[2*i]   : make_float4(0.f,0.f,0.f,0.f);
          float4 f1 = okA ? ((const float4*)src)[2*i+1] : make_float4(0.f,0.f,0.f,0.f);
          u16x8 u;
          u[0]=f2bf(f0.x); u[1]=f2bf(f0.y); u[2]=f2bf(f0.z); u[3]=f2bf(f0.w);
          u[4]=f2bf(f1.x); u[5]=f2bf(f1.y); u[6]=f2bf(f1.z); u[7]=f2bf(f1.w);
          ch[i] = u;
        }
      } else {
        const u16* src = (const u16*)g.A + (size_t)grA*DM + k0 + shf*32;
#pragma unroll
        for (int i = 0; i < 4; i++) ch[i] = okA ? ((const u16x8*)src)[i] : zu;
      }
#pragma unroll
      for (int i = 0; i < 4; i++) {
        int slot = (shf*64 + i*16) ^ ((sr & 7) << 4);
        *(u16x8*)((char*)As + sr*128 + slot) = ch[i];
      }
    }
    // ---- stage B tile (Wt rows, already bf16) ----
    {
      const u16* src = g.W + (size_t)(n0 + sr)*DM + k0 + shf*32;
#pragma unroll
      for (int i = 0; i < 4; i++) {
        u16x8 u = ((const u16x8*)src)[i];
        int slot = (shf*64 + i*16) ^ ((sr & 7) << 4);
        *(u16x8*)((char*)Bs + sr*128 + slot) = u;
      }
    }
    __syncthreads();
    // ---- MFMA ----
#pragma unroll
    for (int kt = 0; kt < 2; kt++) {
      int kbyte = kt*64 + (lane >> 4)*16;
      s16x8 a[4], b[4];
#pragma unroll
      for (int i = 0; i < 4; i++) {
        int row = wr + i*16 + (lane & 15);
        a[i] = *(const s16x8*)((const char*)As + row*128 + (kbyte ^ ((row & 7) << 4)));
      }
#pragma unroll
      for (int j = 0; j < 4; j++) {
        int row = wc + j*16 + (lane & 15);
        b[j] = *(const s16x8*)((const char*)Bs + row*128 + (kbyte ^ ((row & 7) << 4)));
      }
#pragma unroll
      for (int i = 0; i < 4; i++)
#pragma unroll
        for (int j = 0; j < 4; j++)
          acc[i][j] = __builtin_amdgcn_mfma_f32_16x16x32_bf16(a[i], b[j], acc[i][j], 0, 0, 0);
    }
    __syncthreads();
  }

  // ---- epilogue: bias + store ----
#pragma unroll
  for (int j = 0; j < 4; j++) {
    int gcol = n0 + wc + j*16 + (lane & 15);
    float bv = g.bias[gcol];
#pragma unroll
    for (int i = 0; i < 4; i++) {
#pragma unroll
      for (int r = 0; r < 4; r++) {
        int grow = m0 + wr + i*16 + (lane >> 4)*4 + r;
        if (grow < M) {
          float v = acc[i][j][r] + bv;
          if constexpr (CBF16) ((u16*)g.C)[(size_t)grow*DM + gcol] = f2bf(v);
          else                 ((float*)g.C)[(size_t)grow*DM + gcol] = v;
        }
      }
    }
  }
}

// ---------------- fused attention per (b,t,h), 64 q-rows per block ----------------
// grid (5, 768); block 256 (4 waves x 16 q-rows). LDS: K[320][64] (reused for P) + VT[64][320].
__global__ __launch_bounds__(256)
void attn_kernel(const u16* __restrict__ Qb, const u16* __restrict__ Kb,
                 const u16* __restrict__ Vb, const float* __restrict__ mask,
                 u16* __restrict__ attnb){
  __shared__ u16 kw[320*64];   // K rows (swizzled), later P rows [64][320]
  __shared__ u16 vt[64*320];   // V^T (swizzled)
  const int tid = threadIdx.x;
  const int lane = tid & 63;
  const int wid = tid >> 6;
  const int rt  = blockIdx.x;          // q-row tile (0..4)
  const int bth = blockIdx.y;          // (b*T+t)*H + h
  const int h   = bth & 7;
  const int bt  = bth >> 3;
  const size_t base = (size_t)bt * NNODES;

  const u16x8 zu = {0,0,0,0,0,0,0,0};
  const s16x8 zs = {0,0,0,0,0,0,0,0};
  const f32x4 fz = {0.f,0.f,0.f,0.f};

  // ---- stage K (row-major, swizzled) and V^T (transposed, swizzled) ----
  for (int i = tid; i < 320*8; i += 256) {
    int r = i >> 3, c = i & 7;
    u16x8 kv = zu, vv = zu;
    if (r < NNODES) {
      kv = *(const u16x8*)(Kb + (base + r)*DM + h*HDV + c*8);
      vv = *(const u16x8*)(Vb + (base + r)*DM + h*HDV + c*8);
    }
    *(u16x8*)((char*)kw + r*128 + ((c*16) ^ ((r & 7) << 4))) = kv;
#pragma unroll
    for (int j = 0; j < 8; j++) {
      int d = c*8 + j;
      *(u16*)((char*)vt + d*640 + ((r*2) ^ ((d & 7) << 4))) = vv[j];
    }
  }

  // ---- q fragments (global -> regs) ----
  const int qrow = rt*64 + wid*16 + (lane & 15);
  const int kg = (lane >> 4) * 8;
  s16x8 qf[2];
  if (qrow < NNODES) {
    const u16* qp = Qb + (base + qrow)*DM + h*HDV + kg;
    qf[0] = *(const s16x8*)(qp);
    qf[1] = *(const s16x8*)(qp + 32);
  } else { qf[0] = zs; qf[1] = zs; }

  __syncthreads();

  // ---- QK^T: scores 16 rows x 320 cols per wave ----
  f32x4 sc[20];
#pragma unroll
  for (int t = 0; t < 20; t++) sc[t] = fz;
#pragma unroll
  for (int t = 0; t < 20; t++) {
    int m = t*16 + (lane & 15);
#pragma unroll
    for (int kt = 0; kt < 2; kt++) {
      s16x8 kf = *(const s16x8*)((const char*)kw + m*128 + (((kt*32 + kg)*2) ^ ((m & 7) << 4)));
      sc[t] = __builtin_amdgcn_mfma_f32_16x16x32_bf16(qf[kt], kf, sc[t], 0, 0, 0);
    }
  }

  __syncthreads();   // all waves done reading K before overwriting with P

  // ---- softmax over cols (mask-mult first), write P (bf16) into kw ----
  const int nb = rt*64 + wid*16 + (lane >> 4)*4;
  const int mcol = lane & 15;
#pragma unroll
  for (int r = 0; r < 4; r++) {
    int n = nb + r;
    float mx = -INFINITY;
#pragma unroll
    for (int t = 0; t < 20; t++) {
      int m = t*16 + mcol;
      float s;
      if (n < NNODES && m < NNODES) s = sc[t][r] * 0.125f * mask[(size_t)n*NNODES + m];
      else s = -INFINITY;
      sc[t][r] = s;
      mx = fmaxf(mx, s);
    }
#pragma unroll
    for (int d = 1; d < 16; d <<= 1) mx = fmaxf(mx, __shfl_xor(mx, d));
    float sum;
    if (mx == -INFINITY) {           // fully-invalid row (n >= 307)
#pragma unroll
      for (int t = 0; t < 20; t++) sc[t][r] = 0.f;
      sum = 1.f;
    } else {
      sum = 0.f;
#pragma unroll
      for (int t = 0; t < 20; t++) { float e = __expf(sc[t][r] - mx); sc[t][r] = e; sum += e; }
    }
#pragma unroll
    for (int d = 1; d < 16; d <<= 1) sum += __shfl_xor(sum, d);
    float rinv = 1.f / sum;
    int prow = wid*16 + (lane >> 4)*4 + r;
#pragma unroll
    for (int t = 0; t < 20; t++) {
      int m = t*16 + mcol;
      *(u16*)((char*)kw + prow*640 + ((m*2) ^ ((prow & 7) << 4))) = f2bf(sc[t][r] * rinv);
    }
  }
  __syncthreads();

  // ---- PV: out 16 rows x 64 d per wave ----
  f32x4 o[4];
#pragma unroll
  for (int dt = 0; dt < 4; dt++) o[dt] = fz;
  const int arow = wid*16 + (lane & 15);
#pragma unroll
  for (int kn = 0; kn < 10; kn++) {
    int n0b = (kn*32 + kg) * 2;
    s16x8 a = *(const s16x8*)((const char*)kw + arow*640 + (n0b ^ ((arow & 7) << 4)));
#pragma unroll
    for (int dt = 0; dt < 4; dt++) {
      int d = dt*16 + (lane & 15);
      s16x8 b = *(const s16x8*)((const char*)vt + d*640 + (n0b ^ ((d & 7) << 4)));
      o[dt] = __builtin_amdgcn_mfma_f32_16x16x32_bf16(a, b, o[dt], 0, 0, 0);
    }
  }

  // ---- store attention output (bf16) ----
#pragma unroll
  for (int dt = 0; dt < 4; dt++) {
#pragma unroll
    for (int r = 0; r < 4; r++) {
      int n = nb + r;
      if (n < NNODES)
        attnb[(base + n)*DM + h*HDV + dt*16 + (lane & 15)] = f2bf(o[dt][r]);
    }
  }
}

// ---------------- host launcher ----------------
extern "C" void kernel_launch(void* const* d_in, const int* in_sizes, int n_in,
                              void* d_out, int out_size, void* d_ws, size_t ws_size,
                              hipStream_t stream) {
  const float* query = (const float*)d_in[0];
  const float* key   = (const float*)d_in[1];
  const float* value = (const float*)d_in[2];
  const float* sem   = (const float*)d_in[3];
  const float* Wq = (const float*)d_in[4];
  const float* bq = (const float*)d_in[5];
  const float* Wk = (const float*)d_in[6];
  const float* bk = (const float*)d_in[7];
  const float* Wv = (const float*)d_in[8];
  const float* bv = (const float*)d_in[9];
  const float* Wo = (const float*)d_in[10];
  const float* bo = (const float*)d_in[11];
  float* out = (float*)d_out;

  char* ws = (char*)d_ws;
  size_t off = 0;
  auto alloc = [&](size_t b) { size_t o = off; off += (b + 255) & ~(size_t)255; return o; };
  float* mask = (float*)(ws + alloc((size_t)NNODES*NNODES*4));
  u16* wtq = (u16*)(ws + alloc((size_t)DM*DM*2));
  u16* wtk = (u16*)(ws + alloc((size_t)DM*DM*2));
  u16* wtv = (u16*)(ws + alloc((size_t)DM*DM*2));
  u16* wto = (u16*)(ws + alloc((size_t)DM*DM*2));
  u16* qb = (u16*)(ws + alloc((size_t)MROWS*DM*2));
  u16* kb = (u16*)(ws + alloc((size_t)MROWS*DM*2));
  u16* vb = (u16*)(ws + alloc((size_t)MROWS*DM*2));
  u16* ab = (u16*)(ws + alloc((size_t)MROWS*DM*2));
  if (off > ws_size) return;   // scratch too small (deterministic no-op)

  PrepArgs pa;
  pa.w[0] = Wq; pa.w[1] = Wk; pa.w[2] = Wv; pa.w[3] = Wo;
  pa.o[0] = wtq; pa.o[1] = wtk; pa.o[2] = wtv; pa.o[3] = wto;
  prep_w<<<dim3(16,16,4), dim3(32,8,1), 0, stream>>>(pa);

  mask_softmax<<<dim3(NNODES), dim3(256), 0, stream>>>(sem, mask);

  GemmArgs g3;
  g3.s[0] = { query, wtq, bq, qb };
  g3.s[1] = { key,   wtk, bk, kb };
  g3.s[2] = { value, wtv, bv, vb };
  gemm512<1,1><<<dim3((MROWS + 127)/128, 4, 3), dim3(256), 0, stream>>>(g3, MROWS);

  attn_kernel<<<dim3(5, BATCH*TSTEPS*HEADS), dim3(256), 0, stream>>>(qb, kb, vb, mask, ab);

  GemmArgs g1;
  g1.s[0] = { ab, wto, bo, out };
  g1.s[1] = g1.s[0];
  g1.s[2] = g1.s[0];
  gemm512<0,0><<<dim3((MROWS + 127)/128, 4, 1), dim3(256), 0, stream>>>(g1, MROWS);
}

// Round 3
// 509.521 us; speedup vs baseline: 1.3237x; 1.3237x over previous
//
#include <hip/hip_runtime.h>

#define NNODES 307
#define NPAD 320
#define HEADS 8
#define HDV 64
#define DM 512
#define BATCH 8
#define TSTEPS 12
#define MROWS (BATCH*TSTEPS*NNODES)   // 29472

typedef unsigned short u16;
typedef __attribute__((ext_vector_type(8))) short s16x8;
typedef __attribute__((ext_vector_type(8))) unsigned short u16x8;
typedef __attribute__((ext_vector_type(4))) float f32x4;

__device__ __forceinline__ u16 f2bf(float f){
  unsigned int u = __builtin_bit_cast(unsigned int, f);
  u += 0x7fffu + ((u >> 16) & 1u);   // RNE; inputs finite
  return (u16)(u >> 16);
}
__device__ __forceinline__ unsigned f2bf2(float lo, float hi){
  return (unsigned)f2bf(lo) | ((unsigned)f2bf(hi) << 16);
}
__device__ __forceinline__ void glds16(const void* g, void* l){
  __builtin_amdgcn_global_load_lds((const __attribute__((address_space(1))) void*)g,
                                   (__attribute__((address_space(3))) void*)l, 16, 0, 0);
}

// ---------------- weight transpose + bf16 convert: Wt[n][k] = W[k][n] ----------------
struct PrepArgs { const float* w[4]; u16* o[4]; };

__global__ __launch_bounds__(256)
void prep_w(PrepArgs a){
  const float* w = a.w[blockIdx.z];
  u16* o = a.o[blockIdx.z];
  __shared__ float tile[32][33];
  int bx = blockIdx.x*32, by = blockIdx.y*32;
  int tx = threadIdx.x, ty = threadIdx.y;
  for (int i = ty; i < 32; i += 8)
    tile[i][tx] = w[(size_t)(by+i)*DM + bx + tx];
  __syncthreads();
  for (int i = ty; i < 32; i += 8)
    o[(size_t)(bx+i)*DM + by + tx] = f2bf(tile[tx][i]);
}

// ---------------- row softmax of semantic matrix -> padded [320][320], x0.125 folded ----------------
__global__ __launch_bounds__(256)
void mask_softmax(const float* __restrict__ sem, float* __restrict__ maskp){
  int n = blockIdx.x;          // 0..319
  int tid = threadIdx.x, lane = tid & 63, wid = tid >> 6;
  if (n >= NNODES){
    maskp[(size_t)n*NPAD + tid] = 0.f;
    if (tid + 256 < NPAD) maskp[(size_t)n*NPAD + tid + 256] = 0.f;
    return;
  }
  __shared__ float red[4];
  float v0 = sem[(size_t)n*NNODES + tid];
  float v1 = (tid + 256 < NNODES) ? sem[(size_t)n*NNODES + tid + 256] : -INFINITY;
  float mx = fmaxf(v0, v1);
  for (int d = 1; d < 64; d <<= 1) mx = fmaxf(mx, __shfl_xor(mx, d));
  if (lane == 0) red[wid] = mx;
  __syncthreads();
  mx = fmaxf(fmaxf(red[0], red[1]), fmaxf(red[2], red[3]));
  __syncthreads();
  float e0 = __expf(v0 - mx);
  float e1 = (tid + 256 < NNODES) ? __expf(v1 - mx) : 0.f;
  float s = e0 + e1;
  for (int d = 1; d < 64; d <<= 1) s += __shfl_xor(s, d);
  if (lane == 0) red[wid] = s;
  __syncthreads();
  s = red[0] + red[1] + red[2] + red[3];
  float rs = 0.125f / s;    // fold 1/sqrt(hd)=1/8
  maskp[(size_t)n*NPAD + tid] = e0 * rs;
  int c2 = tid + 256;
  if (c2 < NNODES)      maskp[(size_t)n*NPAD + c2] = e1 * rs;
  else if (c2 < NPAD)   maskp[(size_t)n*NPAD + c2] = 0.f;
}

// ---------------- 512-K GEMM: C[M,512] = A[M,512] @ W + bias ----------------
// Wt pre-transposed bf16 [512][512]. LDS XOR-swizzled (16B slot ^ (row&7)).
// B (and bf16 A) staged via global_load_lds with pre-swizzled global source.
struct GemmSet { const void* A; const u16* W; const float* bias; void* C; };
struct GemmArgs { GemmSet s[3]; };

template<int AF32, int CBF16>
__global__ __launch_bounds__(256)
void gemm512(GemmArgs ga, int M){
  GemmSet g = ga.s[blockIdx.y];
  __shared__ u16 As[128*64];
  __shared__ u16 Bs[128*64];
  const int tid = threadIdx.x;
  const int lane = tid & 63;
  const int wid = tid >> 6;

  // bijective chunked XCD swizzle over 924 flat blocks; n-tile inner
  int bid = blockIdx.x;
  const int qch = 924 >> 3, rch = 924 & 7;   // 115, 4
  int xcd = bid & 7, idx = bid >> 3;
  int wg = (xcd < rch ? xcd*(qch+1) : rch*(qch+1) + (xcd-rch)*qch) + idx;
  const int m0 = (wg >> 2) * 128;
  const int n0 = (wg & 3) * 128;
  const int wr = (wid >> 1) * 64;
  const int wc = (wid & 1) * 64;

  const f32x4 fz = {0.f, 0.f, 0.f, 0.f};
  f32x4 acc[4][4];
#pragma unroll
  for (int i = 0; i < 4; i++)
#pragma unroll
    for (int j = 0; j < 4; j++) acc[i][j] = fz;

  // glds lane geometry: wave covers 32 rows (4 issues x 8 rows)
  const int rL = (wid << 5) + (lane >> 3);        // row within tile (for e=0)
  const int cswz = (lane & 7) ^ (rL & 7);         // e*8 doesn't change row&7
  const u16* bsrc = g.W + (size_t)(n0 + rL)*DM + cswz*8;
  const u16* asrcB = AF32 ? nullptr : ((const u16*)g.A + (size_t)(m0 + rL)*DM + cswz*8);

  // fp32-A staging geometry
  const int sr = tid >> 1;
  const int shf = tid & 1;
  const int grA = m0 + sr;
  const bool okA = grA < M;

  for (int k0 = 0; k0 < 512; k0 += 64) {
    // ---- stage B via global_load_lds (pre-swizzled source) ----
#pragma unroll
    for (int e = 0; e < 4; e++)
      glds16(bsrc + (size_t)e*8*DM + k0, Bs + (wid << 11) + (e << 9));
    // ---- stage A ----
    if constexpr (AF32) {
      const float* src = (const float*)g.A + (size_t)grA*DM + k0 + shf*32;
      u16x8 ch[4];
#pragma unroll
      for (int i = 0; i < 4; i++) {
        float4 f0 = okA ? ((const float4*)src)[2*i]   : make_float4(0.f,0.f,0.f,0.f);
        float4 f1 = okA ? ((const float4*)src)[2*i+1] : make_float4(0.f,0.f,0.f,0.f);
        u16x8 u;
        u[0]=f2bf(f0.x); u[1]=f2bf(f0.y); u[2]=f2bf(f0.z); u[3]=f2bf(f0.w);
        u[4]=f2bf(f1.x); u[5]=f2bf(f1.y); u[6]=f2bf(f1.z); u[7]=f2bf(f1.w);
        ch[i] = u;
      }
#pragma unroll
      for (int i = 0; i < 4; i++) {
        int slot = (shf*64 + i*16) ^ ((sr & 7) << 4);
        *(u16x8*)((char*)As + sr*128 + slot) = ch[i];
      }
    } else {
#pragma unroll
      for (int e = 0; e < 4; e++)
        glds16(asrcB + (size_t)e*8*DM + k0, As + (wid << 11) + (e << 9));
    }
    __syncthreads();
    // ---- MFMA ----
    __builtin_amdgcn_s_setprio(1);
#pragma unroll
    for (int kt = 0; kt < 2; kt++) {
      int kbyte = kt*64 + (lane >> 4)*16;
      s16x8 a[4], b[4];
#pragma unroll
      for (int i = 0; i < 4; i++) {
        int row = wr + i*16 + (lane & 15);
        a[i] = *(const s16x8*)((const char*)As + row*128 + (kbyte ^ ((row & 7) << 4)));
      }
#pragma unroll
      for (int j = 0; j < 4; j++) {
        int row = wc + j*16 + (lane & 15);
        b[j] = *(const s16x8*)((const char*)Bs + row*128 + (kbyte ^ ((row & 7) << 4)));
      }
#pragma unroll
      for (int i = 0; i < 4; i++)
#pragma unroll
        for (int j = 0; j < 4; j++)
          acc[i][j] = __builtin_amdgcn_mfma_f32_16x16x32_bf16(a[i], b[j], acc[i][j], 0, 0, 0);
    }
    __builtin_amdgcn_s_setprio(0);
    __syncthreads();
  }

  // ---- epilogue: bias + store ----
#pragma unroll
  for (int j = 0; j < 4; j++) {
    int gcol = n0 + wc + j*16 + (lane & 15);
    float bv = g.bias[gcol];
#pragma unroll
    for (int i = 0; i < 4; i++) {
#pragma unroll
      for (int r = 0; r < 4; r++) {
        int grow = m0 + wr + i*16 + (lane >> 4)*4 + r;
        if (grow < M) {
          float v = acc[i][j][r] + bv;
          if constexpr (CBF16) ((u16*)g.C)[(size_t)grow*DM + gcol] = f2bf(v);
          else                 ((float*)g.C)[(size_t)grow*DM + gcol] = v;
        }
      }
    }
  }
}

// ---------------- fused attention: one block per (b,t,h), 640 threads = 10 waves ----------------
// Swapped QK^T (mfma(K,Q)) => lane owns a full score-row quarter; coalesced float4 mask loads;
// per-wave rotating P buffer in LDS (same-wave in-order LDS, no barrier).
__global__ __launch_bounds__(640, 3)
void attn_kernel(const u16* __restrict__ Qb, const u16* __restrict__ Kb,
                 const u16* __restrict__ Vb, const float* __restrict__ maskp,
                 u16* __restrict__ attnb){
  __shared__ u16 kw[NPAD*64];      // K rows, swizzled          (40 KB)
  __shared__ u16 vt[64*NPAD];      // V^T, swizzled             (40 KB)
  __shared__ u16 pb[10*2*16*40];   // per-wave P dbuf [2][16][40] (25 KB)
  const int tid = threadIdx.x;
  const int lane = tid & 63;
  const int wid = tid >> 6;
  const int qq = lane & 15;
  const int gg = lane >> 4;
  const int bth = blockIdx.x;          // (b*T+t)*H + h
  const int h   = bth & 7;
  const int bt  = bth >> 3;
  const size_t base = (size_t)bt * NNODES;

  const u16x8 zu = {0,0,0,0,0,0,0,0};
  const s16x8 zs = {0,0,0,0,0,0,0,0};
  const f32x4 fz = {0.f,0.f,0.f,0.f};

  // ---- q fragments for both q-tiles of this wave (issued before staging) ----
  s16x8 qf[2][2];
#pragma unroll
  for (int s = 0; s < 2; s++) {
    int qt = wid*2 + s;
    int qrow = qt*16 + qq;
    if (qrow < NNODES) {
      const u16* qp = Qb + (base + qrow)*DM + h*HDV + gg*8;
      qf[s][0] = *(const s16x8*)(qp);
      qf[s][1] = *(const s16x8*)(qp + 32);
    } else { qf[s][0] = zs; qf[s][1] = zs; }
  }

  // ---- stage K (row-major, swizzled) and V^T (transposed, swizzled) ----
  for (int i = tid; i < NPAD*8; i += 640) {
    int r = i >> 3, c = i & 7;
    u16x8 kv = zu, vv = zu;
    if (r < NNODES) {
      kv = *(const u16x8*)(Kb + (base + r)*DM + h*HDV + c*8);
      vv = *(const u16x8*)(Vb + (base + r)*DM + h*HDV + c*8);
    }
    *(u16x8*)((char*)kw + r*128 + ((c*16) ^ ((r & 7) << 4))) = kv;
#pragma unroll
    for (int j = 0; j < 8; j++) {
      int d = c*8 + j;
      *(u16*)((char*)vt + d*640 + ((r*2) ^ ((d & 7) << 4))) = vv[j];
    }
  }
  __syncthreads();

  u16* pbw = pb + wid*1280;      // this wave's P buffer (u16 elems)

#pragma unroll
  for (int s = 0; s < 2; s++) {
    const int qt = wid*2 + s;
    const int n = qt*16 + qq;    // this lane's q-row (score-row owner)

    // ---- QK^T (swapped): sc[t][r] = S[n][m = t*16 + 4*gg + r] ----
    f32x4 sc[20];
#pragma unroll
    for (int t = 0; t < 20; t++) sc[t] = fz;
    __builtin_amdgcn_s_setprio(1);
#pragma unroll
    for (int t = 0; t < 20; t++) {
      int m = t*16 + qq;
#pragma unroll
      for (int kt = 0; kt < 2; kt++) {
        s16x8 kf = *(const s16x8*)((const char*)kw + m*128 + ((kt*64 + gg*16) ^ ((m & 7) << 4)));
        sc[t] = __builtin_amdgcn_mfma_f32_16x16x32_bf16(kf, qf[s][kt], sc[t], 0, 0, 0);
      }
    }
    __builtin_amdgcn_s_setprio(0);

    // ---- masked softmax (lane-local row; mask*0.125 pre-folded, coalesced float4) ----
    const float* mrow = maskp + (size_t)n*NPAD + gg*4;
#pragma unroll
    for (int t = 0; t < 20; t++) {
      float4 mk = *(const float4*)(mrow + t*16);
      sc[t][0] *= mk.x; sc[t][1] *= mk.y; sc[t][2] *= mk.z; sc[t][3] *= mk.w;
    }
#pragma unroll
    for (int r = 0; r < 4; r++)
      if (304 + gg*4 + r >= NNODES) sc[19][r] = -1e30f;

    float mx = -1e30f;
#pragma unroll
    for (int t = 0; t < 20; t++)
      mx = fmaxf(fmaxf(fmaxf(mx, sc[t][0]), fmaxf(sc[t][1], sc[t][2])), sc[t][3]);
    mx = fmaxf(mx, __shfl_xor(mx, 16));
    mx = fmaxf(mx, __shfl_xor(mx, 32));

    float sum = 0.f;
#pragma unroll
    for (int t = 0; t < 20; t++) {
#pragma unroll
      for (int r = 0; r < 4; r++) { float e = __expf(sc[t][r] - mx); sc[t][r] = e; sum += e; }
    }
    sum += __shfl_xor(sum, 16);
    sum += __shfl_xor(sum, 32);
    const float rinv = 1.f / sum;

    // ---- PV with per-kt P round-trip through wave-private LDS ----
    f32x4 o[4];
#pragma unroll
    for (int dt = 0; dt < 4; dt++) o[dt] = fz;
#pragma unroll
    for (int kt = 0; kt < 10; kt++) {
      u16* ps = pbw + (kt & 1)*640;
      uint2 w0, w1;
      w0.x = f2bf2(sc[2*kt][0]*rinv,   sc[2*kt][1]*rinv);
      w0.y = f2bf2(sc[2*kt][2]*rinv,   sc[2*kt][3]*rinv);
      w1.x = f2bf2(sc[2*kt+1][0]*rinv, sc[2*kt+1][1]*rinv);
      w1.y = f2bf2(sc[2*kt+1][2]*rinv, sc[2*kt+1][3]*rinv);
      *(uint2*)(ps + qq*40 + gg*4)      = w0;   // m-local 4g..4g+3
      *(uint2*)(ps + qq*40 + 16 + gg*4) = w1;   // m-local 16+4g..
      s16x8 pa = *(const s16x8*)(ps + qq*40 + gg*8);   // A-frag: P[q][8g..8g+7]
      __builtin_amdgcn_s_setprio(1);
#pragma unroll
      for (int dt = 0; dt < 4; dt++) {
        int d = dt*16 + qq;
        s16x8 vb = *(const s16x8*)((const char*)vt + d*640 + ((kt*64 + gg*16) ^ ((d & 7) << 4)));
        o[dt] = __builtin_amdgcn_mfma_f32_16x16x32_bf16(pa, vb, o[dt], 0, 0, 0);
      }
      __builtin_amdgcn_s_setprio(0);
    }

    // ---- store (row = 4g+r, col = qq within d-tile) ----
#pragma unroll
    for (int dt = 0; dt < 4; dt++) {
#pragma unroll
      for (int r = 0; r < 4; r++) {
        int nn = qt*16 + gg*4 + r;
        if (nn < NNODES)
          attnb[(base + nn)*DM + h*HDV + dt*16 + qq] = f2bf(o[dt][r]);
      }
    }
  }
}

// ---------------- host launcher ----------------
extern "C" void kernel_launch(void* const* d_in, const int* in_sizes, int n_in,
                              void* d_out, int out_size, void* d_ws, size_t ws_size,
                              hipStream_t stream) {
  const float* query = (const float*)d_in[0];
  const float* key   = (const float*)d_in[1];
  const float* value = (const float*)d_in[2];
  const float* sem   = (const float*)d_in[3];
  const float* Wq = (const float*)d_in[4];
  const float* bq = (const float*)d_in[5];
  const float* Wk = (const float*)d_in[6];
  const float* bk = (const float*)d_in[7];
  const float* Wv = (const float*)d_in[8];
  const float* bv = (const float*)d_in[9];
  const float* Wo = (const float*)d_in[10];
  const float* bo = (const float*)d_in[11];
  float* out = (float*)d_out;

  char* ws = (char*)d_ws;
  size_t off = 0;
  auto alloc = [&](size_t b) { size_t o = off; off += (b + 255) & ~(size_t)255; return o; };
  float* maskp = (float*)(ws + alloc((size_t)NPAD*NPAD*4));
  u16* wtq = (u16*)(ws + alloc((size_t)DM*DM*2));
  u16* wtk = (u16*)(ws + alloc((size_t)DM*DM*2));
  u16* wtv = (u16*)(ws + alloc((size_t)DM*DM*2));
  u16* wto = (u16*)(ws + alloc((size_t)DM*DM*2));
  u16* ab = (u16*)(ws + alloc((size_t)MROWS*DM*2));   // before qb: OOB glds rows land in qb
  u16* qb = (u16*)(ws + alloc((size_t)MROWS*DM*2));
  u16* kb = (u16*)(ws + alloc((size_t)MROWS*DM*2));
  u16* vb = (u16*)(ws + alloc((size_t)MROWS*DM*2));
  if (off > ws_size) return;

  PrepArgs pa;
  pa.w[0] = Wq; pa.w[1] = Wk; pa.w[2] = Wv; pa.w[3] = Wo;
  pa.o[0] = wtq; pa.o[1] = wtk; pa.o[2] = wtv; pa.o[3] = wto;
  prep_w<<<dim3(16,16,4), dim3(32,8,1), 0, stream>>>(pa);

  mask_softmax<<<dim3(NPAD), dim3(256), 0, stream>>>(sem, maskp);

  GemmArgs g3;
  g3.s[0] = { query, wtq, bq, qb };
  g3.s[1] = { key,   wtk, bk, kb };
  g3.s[2] = { value, wtv, bv, vb };
  gemm512<1,1><<<dim3(924, 3), dim3(256), 0, stream>>>(g3, MROWS);

  attn_kernel<<<dim3(BATCH*TSTEPS*HEADS), dim3(640), 0, stream>>>(qb, kb, vb, maskp, ab);

  GemmArgs g1;
  g1.s[0] = { ab, wto, bo, out };
  g1.s[1] = g1.s[0];
  g1.s[2] = g1.s[0];
  gemm512<0,0><<<dim3(924, 1), dim3(256), 0, stream>>>(g1, MROWS);
}

// Round 5
// 444.994 us; speedup vs baseline: 1.5156x; 1.1450x over previous
//
#include <hip/hip_runtime.h>

#define NNODES 307
#define NPAD 320
#define HEADS 8
#define HDV 64
#define DM 512
#define BATCH 8
#define TSTEPS 12
#define MROWS (BATCH*TSTEPS*NNODES)   // 29472

typedef unsigned short u16;
typedef __attribute__((ext_vector_type(8))) short s16x8;
typedef __attribute__((ext_vector_type(8))) unsigned short u16x8;
typedef __attribute__((ext_vector_type(4))) float f32x4;

__device__ __forceinline__ u16 f2bf(float f){
  unsigned int u = __builtin_bit_cast(unsigned int, f);
  u += 0x7fffu + ((u >> 16) & 1u);   // RNE; inputs finite
  return (u16)(u >> 16);
}
__device__ __forceinline__ unsigned f2bf2(float lo, float hi){
  return (unsigned)f2bf(lo) | ((unsigned)f2bf(hi) << 16);
}
__device__ __forceinline__ void glds16(const void* g, void* l){
  __builtin_amdgcn_global_load_lds((const __attribute__((address_space(1))) void*)g,
                                   (__attribute__((address_space(3))) void*)l, 16, 0, 0);
}

// ---------------- weight transpose + bf16 convert: Wt[n][k] = W[k][n] ----------------
struct PrepArgs { const float* w[4]; u16* o[4]; };

__global__ __launch_bounds__(256)
void prep_w(PrepArgs a){
  const float* w = a.w[blockIdx.z];
  u16* o = a.o[blockIdx.z];
  __shared__ float tile[32][33];
  int bx = blockIdx.x*32, by = blockIdx.y*32;
  int tx = threadIdx.x, ty = threadIdx.y;
  for (int i = ty; i < 32; i += 8)
    tile[i][tx] = w[(size_t)(by+i)*DM + bx + tx];
  __syncthreads();
  for (int i = ty; i < 32; i += 8)
    o[(size_t)(bx+i)*DM + by + tx] = f2bf(tile[tx][i]);
}

// ---------------- row softmax of semantic matrix -> padded [320][320], x0.125 folded ----------------
__global__ __launch_bounds__(256)
void mask_softmax(const float* __restrict__ sem, float* __restrict__ maskp){
  int n = blockIdx.x;          // 0..319
  int tid = threadIdx.x, lane = tid & 63, wid = tid >> 6;
  if (n >= NNODES){
    maskp[(size_t)n*NPAD + tid] = 0.f;
    if (tid + 256 < NPAD) maskp[(size_t)n*NPAD + tid + 256] = 0.f;
    return;
  }
  __shared__ float red[4];
  float v0 = sem[(size_t)n*NNODES + tid];
  float v1 = (tid + 256 < NNODES) ? sem[(size_t)n*NNODES + tid + 256] : -INFINITY;
  float mx = fmaxf(v0, v1);
  for (int d = 1; d < 64; d <<= 1) mx = fmaxf(mx, __shfl_xor(mx, d));
  if (lane == 0) red[wid] = mx;
  __syncthreads();
  mx = fmaxf(fmaxf(red[0], red[1]), fmaxf(red[2], red[3]));
  __syncthreads();
  float e0 = __expf(v0 - mx);
  float e1 = (tid + 256 < NNODES) ? __expf(v1 - mx) : 0.f;
  float s = e0 + e1;
  for (int d = 1; d < 64; d <<= 1) s += __shfl_xor(s, d);
  if (lane == 0) red[wid] = s;
  __syncthreads();
  s = red[0] + red[1] + red[2] + red[3];
  float rs = 0.125f / s;    // fold 1/sqrt(hd)=1/8
  maskp[(size_t)n*NPAD + tid] = e0 * rs;
  int c2 = tid + 256;
  if (c2 < NNODES)      maskp[(size_t)n*NPAD + c2] = e1 * rs;
  else if (c2 < NPAD)   maskp[(size_t)n*NPAD + c2] = 0.f;
}

// ---------------- 512-K GEMM: C[M,512] = A[M,512] @ W + bias ----------------
// Double-buffered LDS pipeline (T3-min): prefetch tile t+1 before MFMA of t,
// one barrier per K-step. B (and bf16-A) via global_load_lds w/ pre-swizzled src.
// bf16-C epilogue repacks through LDS for coalesced u16x8 stores.
struct GemmSet { const void* A; const u16* W; const float* bias; void* C; };
struct GemmArgs { GemmSet s[3]; };

template<int AF32, int CBF16>
__global__ __launch_bounds__(256)
void gemm512(GemmArgs ga, int M){
  GemmSet g = ga.s[blockIdx.y];
  __shared__ u16 lds[32768];   // 64 KB: buf c at c*16384 (A: 8192 u16, B: 8192 u16)
  const int tid = threadIdx.x;
  const int lane = tid & 63;
  const int wid = tid >> 6;
  const int qq = lane & 15, gg = lane >> 4;

  // bijective chunked XCD swizzle over 924 flat blocks; n-tile inner
  int bid = blockIdx.x;
  const int qch = 924 >> 3, rch = 924 & 7;   // 115, 4
  int xcd = bid & 7, idx = bid >> 3;
  int wg = (xcd < rch ? xcd*(qch+1) : rch*(qch+1) + (xcd-rch)*qch) + idx;
  const int m0 = (wg >> 2) * 128;
  const int n0 = (wg & 3) * 128;
  const int wr = (wid >> 1) * 64;
  const int wc = (wid & 1) * 64;

  const f32x4 fz = {0.f, 0.f, 0.f, 0.f};
  f32x4 acc[4][4];
#pragma unroll
  for (int i = 0; i < 4; i++)
#pragma unroll
    for (int j = 0; j < 4; j++) acc[i][j] = fz;

  // glds lane geometry: wave covers 32 rows (4 issues x 8 rows)
  const int rL = (wid << 5) + (lane >> 3);
  const int cswz = (lane & 7) ^ (rL & 7);
  const u16* bsrc = g.W + (size_t)(n0 + rL)*DM + cswz*8;
  const u16* asrcB = (const u16*)g.A + (size_t)(m0 + rL)*DM + cswz*8;
  const int ldst = (wid << 11);   // wave's dest region (u16)

  // fp32-A reg staging geometry
  const int sr = tid >> 1;
  const int shf = tid & 1;
  const float* aptr = (const float*)g.A + (size_t)(m0 + sr)*DM + shf*32;
  const bool okA = (m0 + sr) < M;

  auto stageB = [&](int c, int k0){
    u16* dst = lds + c*16384 + 8192 + ldst;
#pragma unroll
    for (int e = 0; e < 4; e++)
      glds16(bsrc + (size_t)(e*8)*DM + k0, dst + (e << 9));
  };
  auto stageAg = [&](int c, int k0){
    u16* dst = lds + c*16384 + ldst;
#pragma unroll
    for (int e = 0; e < 4; e++)
      glds16(asrcB + (size_t)(e*8)*DM + k0, dst + (e << 9));
  };
  auto loadA = [&](float4* An, int k0){
#pragma unroll
    for (int i = 0; i < 8; i++)
      An[i] = okA ? ((const float4*)(aptr + k0))[i] : make_float4(0.f,0.f,0.f,0.f);
  };
  auto writeA = [&](const float4* An, int c){
    u16* Abuf = lds + c*16384;
#pragma unroll
    for (int i = 0; i < 4; i++) {
      float4 f0 = An[2*i], f1 = An[2*i+1];
      u16x8 u;
      u[0]=f2bf(f0.x); u[1]=f2bf(f0.y); u[2]=f2bf(f0.z); u[3]=f2bf(f0.w);
      u[4]=f2bf(f1.x); u[5]=f2bf(f1.y); u[6]=f2bf(f1.z); u[7]=f2bf(f1.w);
      int slot = (shf*64 + i*16) ^ ((sr & 7) << 4);
      *(u16x8*)((char*)Abuf + sr*128 + slot) = u;
    }
  };
  auto compute = [&](int c){
    const char* Abuf = (const char*)(lds + c*16384);
    const char* Bbuf = Abuf + 16384;   // bytes
    __builtin_amdgcn_s_setprio(1);
#pragma unroll
    for (int kt = 0; kt < 2; kt++) {
      int kbyte = kt*64 + gg*16;
      s16x8 a[4], b[4];
#pragma unroll
      for (int i = 0; i < 4; i++) {
        int row = wr + i*16 + qq;
        a[i] = *(const s16x8*)(Abuf + row*128 + (kbyte ^ ((row & 7) << 4)));
      }
#pragma unroll
      for (int j = 0; j < 4; j++) {
        int row = wc + j*16 + qq;
        b[j] = *(const s16x8*)(Bbuf + row*128 + (kbyte ^ ((row & 7) << 4)));
      }
#pragma unroll
      for (int i = 0; i < 4; i++)
#pragma unroll
        for (int j = 0; j < 4; j++)
          acc[i][j] = __builtin_amdgcn_mfma_f32_16x16x32_bf16(a[i], b[j], acc[i][j], 0, 0, 0);
    }
    __builtin_amdgcn_s_setprio(0);
  };

  // ---- pipeline ----
  float4 An[8];
  if constexpr (AF32) { loadA(An, 0); stageB(0, 0); writeA(An, 0); }
  else { stageAg(0, 0); stageB(0, 0); }
  __syncthreads();

#pragma unroll
  for (int t = 0; t < 8; t++) {
    const int cur = t & 1;
    if (t < 7) {
      if constexpr (AF32) loadA(An, (t+1)*64);
      else stageAg(cur^1, (t+1)*64);
      stageB(cur^1, (t+1)*64);
    }
    compute(cur);
    if constexpr (AF32) { if (t < 7) writeA(An, cur^1); }
    __syncthreads();
  }

  // ---- epilogue ----
  if constexpr (CBF16) {
    u16* ct = lds;                     // [128][136] u16 (16B-aligned rows, pad kills conflicts)
#pragma unroll
    for (int j = 0; j < 4; j++) {
      float bv = g.bias[n0 + wc + j*16 + qq];
#pragma unroll
      for (int i = 0; i < 4; i++)
#pragma unroll
        for (int r = 0; r < 4; r++)
          ct[(wr + i*16 + gg*4 + r)*136 + wc + j*16 + qq] = f2bf(acc[i][j][r] + bv);
    }
    __syncthreads();
#pragma unroll
    for (int it = 0; it < 8; it++) {
      int i = tid + it*256;
      int row = i >> 4, seg = i & 15;
      if (m0 + row < M)
        *(u16x8*)((u16*)g.C + (size_t)(m0+row)*DM + n0 + seg*8) =
            *(const u16x8*)(ct + row*136 + seg*8);
    }
  } else {
#pragma unroll
    for (int j = 0; j < 4; j++) {
      int gcol = n0 + wc + j*16 + qq;
      float bv = g.bias[gcol];
#pragma unroll
      for (int i = 0; i < 4; i++)
#pragma unroll
        for (int r = 0; r < 4; r++) {
          int grow = m0 + wr + i*16 + gg*4 + r;
          if (grow < M) ((float*)g.C)[(size_t)grow*DM + gcol] = acc[i][j][r] + bv;
        }
    }
  }
}

// ---------------- fused attention: flash over 2 K/V-halves of 160 rows ----------------
// 256 threads (4 waves x 16 q-rows), grid (5, 768). LDS 49 KB -> 3 blocks/CU.
// Swapped QK^T (lane owns a full score row), online softmax with cross-lane rescale.
__global__ __launch_bounds__(256, 3)
void attn_kernel(const u16* __restrict__ Qb, const u16* __restrict__ Kb,
                 const u16* __restrict__ Vb, const float* __restrict__ maskp,
                 u16* __restrict__ attnb){
  __shared__ u16 kw[160*64];     // K half, swizzled rows (20 KB); reused for output repack
  __shared__ u16 vt[64*192];     // V^T half, 384B row stride, swizzled (24 KB)
  __shared__ u16 pb[4*16*40];    // per-wave P buffer (5 KB)
  const int tid = threadIdx.x;
  const int lane = tid & 63;
  const int wid = tid >> 6;
  const int qq = lane & 15;
  const int gg = lane >> 4;
  const int qt = blockIdx.x * 4 + wid;     // q-tile 0..19
  const int bth = blockIdx.y;              // (b*T+t)*H + h
  const int h   = bth & 7;
  const int bt  = bth >> 3;
  const size_t base = (size_t)bt * NNODES;
  const int n = qt*16 + qq;                // this lane's q-row

  const u16x8 zu = {0,0,0,0,0,0,0,0};
  const s16x8 zs = {0,0,0,0,0,0,0,0};
  const f32x4 fz = {0.f,0.f,0.f,0.f};

  // q fragments (loaded once)
  s16x8 qf[2];
  if (n < NNODES) {
    const u16* qp = Qb + (base + n)*DM + h*HDV + gg*8;
    qf[0] = *(const s16x8*)(qp);
    qf[1] = *(const s16x8*)(qp + 32);
  } else { qf[0] = zs; qf[1] = zs; }

  f32x4 o[4] = {fz, fz, fz, fz};
  float m_run = -1e30f, l_run = 0.f;
  u16* pbw = pb + wid*640;

  for (int hf = 0; hf < 2; hf++) {
    // ---- stage K half (row-major swizzled) + V^T half ----
    for (int i = tid; i < 160*8; i += 256) {
      int rl = i >> 3, c = i & 7, gr = hf*160 + rl;
      u16x8 kv = zu, vv = zu;
      if (gr < NNODES) {
        kv = *(const u16x8*)(Kb + (base + gr)*DM + h*HDV + c*8);
        vv = *(const u16x8*)(Vb + (base + gr)*DM + h*HDV + c*8);
      }
      *(u16x8*)((char*)kw + rl*128 + ((c*16) ^ ((rl & 7) << 4))) = kv;
#pragma unroll
      for (int j = 0; j < 8; j++) {
        int d = c*8 + j;
        *(u16*)((char*)vt + d*384 + ((rl*2) ^ ((d & 7) << 4))) = vv[j];
      }
    }
    __syncthreads();

    // ---- QK^T (swapped): sc[t][r] = S[n][hf*160 + t*16 + 4*gg + r] ----
    f32x4 sc[10];
#pragma unroll
    for (int t = 0; t < 10; t++) sc[t] = fz;
    __builtin_amdgcn_s_setprio(1);
#pragma unroll
    for (int t = 0; t < 10; t++) {
      int ml = t*16 + qq;
#pragma unroll
      for (int kt = 0; kt < 2; kt++) {
        s16x8 kf = *(const s16x8*)((const char*)kw + ml*128 + ((kt*64 + gg*16) ^ ((ml & 7) << 4)));
        sc[t] = __builtin_amdgcn_mfma_f32_16x16x32_bf16(kf, qf[kt], sc[t], 0, 0, 0);
      }
    }
    __builtin_amdgcn_s_setprio(0);

    // ---- multiplicative mask (0.125 pre-folded), coalesced float4 ----
    const float* mrow = maskp + (size_t)n*NPAD + hf*160 + gg*4;
#pragma unroll
    for (int t = 0; t < 10; t++) {
      float4 mk = *(const float4*)(mrow + t*16);
      sc[t][0] *= mk.x; sc[t][1] *= mk.y; sc[t][2] *= mk.z; sc[t][3] *= mk.w;
    }
    if (hf) {   // tail: m = 304 + gg*4 + r
#pragma unroll
      for (int r = 0; r < 4; r++)
        if (304 + gg*4 + r >= NNODES) sc[9][r] = -1e30f;
    }

    // ---- online softmax update (row stats identical across the 4 gg lanes) ----
    float mh = -1e30f;
#pragma unroll
    for (int t = 0; t < 10; t++)
      mh = fmaxf(fmaxf(fmaxf(mh, sc[t][0]), fmaxf(sc[t][1], sc[t][2])), sc[t][3]);
    mh = fmaxf(mh, __shfl_xor(mh, 16));
    mh = fmaxf(mh, __shfl_xor(mh, 32));
    float mnew = fmaxf(m_run, mh);
    float scl = __expf(m_run - mnew);    // 0 on first half
    m_run = mnew;
    float sum = 0.f;
#pragma unroll
    for (int t = 0; t < 10; t++) {
#pragma unroll
      for (int r = 0; r < 4; r++) { float e = __expf(sc[t][r] - mnew); sc[t][r] = e; sum += e; }
    }
    sum += __shfl_xor(sum, 16);
    sum += __shfl_xor(sum, 32);
    l_run = l_run * scl + sum;
    float srs[4];
#pragma unroll
    for (int r = 0; r < 4; r++) srs[r] = __shfl(scl, gg*4 + r);   // scale for o's rows
#pragma unroll
    for (int dt = 0; dt < 4; dt++) {
      o[dt][0] *= srs[0]; o[dt][1] *= srs[1]; o[dt][2] *= srs[2]; o[dt][3] *= srs[3];
    }

    // ---- PV: unnormalized P via wave-private LDS round-trip (same-wave in-order) ----
#pragma unroll
    for (int kt = 0; kt < 5; kt++) {
      uint2 w0, w1;
      w0.x = f2bf2(sc[2*kt][0],   sc[2*kt][1]);
      w0.y = f2bf2(sc[2*kt][2],   sc[2*kt][3]);
      w1.x = f2bf2(sc[2*kt+1][0], sc[2*kt+1][1]);
      w1.y = f2bf2(sc[2*kt+1][2], sc[2*kt+1][3]);
      *(uint2*)(pbw + qq*40 + gg*4)      = w0;
      *(uint2*)(pbw + qq*40 + 16 + gg*4) = w1;
      s16x8 pa = *(const s16x8*)(pbw + qq*40 + gg*8);
      __builtin_amdgcn_s_setprio(1);
#pragma unroll
      for (int dt = 0; dt < 4; dt++) {
        int d = dt*16 + qq;
        s16x8 vbf = *(const s16x8*)((const char*)vt + d*384 + ((kt*64 + gg*16) ^ ((d & 7) << 4)));
        o[dt] = __builtin_amdgcn_mfma_f32_16x16x32_bf16(pa, vbf, o[dt], 0, 0, 0);
      }
      __builtin_amdgcn_s_setprio(0);
    }
    __syncthreads();   // all waves done with kw/vt before restage / epilogue reuse
  }

  // ---- finalize: normalize rows, repack via LDS, coalesced 32B/lane stores ----
  float li[4];
#pragma unroll
  for (int r = 0; r < 4; r++) li[r] = 1.f / __shfl(l_run, gg*4 + r);
  u16* ow = kw + wid*1152;     // per-wave [16][72] u16
#pragma unroll
  for (int dt = 0; dt < 4; dt++)
#pragma unroll
    for (int r = 0; r < 4; r++)
      ow[(gg*4 + r)*72 + dt*16 + qq] = f2bf(o[dt][r] * li[r]);
  // same-wave in-order LDS: reads below see this wave's writes
  {
    int row = lane >> 2, segb = (lane & 3)*16;
    int nn = qt*16 + row;
    if (nn < NNODES) {
      u16* dst = attnb + (base + nn)*DM + h*HDV + segb;
      *(u16x8*)(dst)     = *(const u16x8*)(ow + row*72 + segb);
      *(u16x8*)(dst + 8) = *(const u16x8*)(ow + row*72 + segb + 8);
    }
  }
}

// ---------------- host launcher ----------------
extern "C" void kernel_launch(void* const* d_in, const int* in_sizes, int n_in,
                              void* d_out, int out_size, void* d_ws, size_t ws_size,
                              hipStream_t stream) {
  const float* query = (const float*)d_in[0];
  const float* key   = (const float*)d_in[1];
  const float* value = (const float*)d_in[2];
  const float* sem   = (const float*)d_in[3];
  const float* Wq = (const float*)d_in[4];
  const float* bq = (const float*)d_in[5];
  const float* Wk = (const float*)d_in[6];
  const float* bk = (const float*)d_in[7];
  const float* Wv = (const float*)d_in[8];
  const float* bv = (const float*)d_in[9];
  const float* Wo = (const float*)d_in[10];
  const float* bo = (const float*)d_in[11];
  float* out = (float*)d_out;

  char* ws = (char*)d_ws;
  size_t off = 0;
  auto alloc = [&](size_t b) { size_t o = off; off += (b + 255) & ~(size_t)255; return o; };
  float* maskp = (float*)(ws + alloc((size_t)NPAD*NPAD*4));
  u16* wtq = (u16*)(ws + alloc((size_t)DM*DM*2));
  u16* wtk = (u16*)(ws + alloc((size_t)DM*DM*2));
  u16* wtv = (u16*)(ws + alloc((size_t)DM*DM*2));
  u16* wto = (u16*)(ws + alloc((size_t)DM*DM*2));
  u16* ab = (u16*)(ws + alloc((size_t)MROWS*DM*2));   // before qb: OOB glds rows land in qb
  u16* qb = (u16*)(ws + alloc((size_t)MROWS*DM*2));
  u16* kb = (u16*)(ws + alloc((size_t)MROWS*DM*2));
  u16* vb = (u16*)(ws + alloc((size_t)MROWS*DM*2));
  if (off > ws_size) return;

  PrepArgs pa;
  pa.w[0] = Wq; pa.w[1] = Wk; pa.w[2] = Wv; pa.w[3] = Wo;
  pa.o[0] = wtq; pa.o[1] = wtk; pa.o[2] = wtv; pa.o[3] = wto;
  prep_w<<<dim3(16,16,4), dim3(32,8,1), 0, stream>>>(pa);

  mask_softmax<<<dim3(NPAD), dim3(256), 0, stream>>>(sem, maskp);

  GemmArgs g3;
  g3.s[0] = { query, wtq, bq, qb };
  g3.s[1] = { key,   wtk, bk, kb };
  g3.s[2] = { value, wtv, bv, vb };
  gemm512<1,1><<<dim3(924, 3), dim3(256), 0, stream>>>(g3, MROWS);

  attn_kernel<<<dim3(5, BATCH*TSTEPS*HEADS), dim3(256), 0, stream>>>(qb, kb, vb, maskp, ab);

  GemmArgs g1;
  g1.s[0] = { ab, wto, bo, out };
  g1.s[1] = g1.s[0];
  g1.s[2] = g1.s[0];
  gemm512<0,0><<<dim3(924, 1), dim3(256), 0, stream>>>(g1, MROWS);
}